// Round 9
// baseline (217.217 us; speedup 1.0000x reference)
//
#include <hip/hip_runtime.h>

typedef float f4 __attribute__((ext_vector_type(4)));

// ---------------------------------------------------------------------------
// R9: sequential-front restructure. Consecutive blocks -> consecutive 64-row
// output tiles (33 KB apart) so the resident ~1024 blocks form one compact
// sliding window over x and out (copy/fill-like DRAM pattern), instead of
// 2048 scattered per-segment streams. K1 precomputes offsets + fast-tile
// scans + a flat tile->(seg,loc) map in d_ws. K2 does one tile per block
// with the proven full-line wave-private LDS-bounce body; trailing blocks
// handle ragged tails (empty for uniform lengths).
// ---------------------------------------------------------------------------

__global__ __launch_bounds__(1024) void scan_kernel(const int* __restrict__ lengths,
                                                    int* __restrict__ offsets,
                                                    int* __restrict__ tprefix,
                                                    int* __restrict__ seg_of,
                                                    int* __restrict__ loc_of,
                                                    int n_seg, int use_map) {
    __shared__ int wsum[16];
    __shared__ int carry[2];              // [0]=row carry, [1]=tile carry
    const int t = threadIdx.x;
    const int lane = t & 63, wave = t >> 6;
    if (t == 0) { carry[0] = 0; carry[1] = 0; }
    __syncthreads();

    for (int base = 0; base < n_seg; base += 2048) {
        const int i0 = base + 2 * t, i1 = i0 + 1;
        const int a = (i0 < n_seg) ? lengths[i0] : 0;
        const int b = (i1 < n_seg) ? lengths[i1] : 0;
        const int sum2 = a + b;

        // ---- scan of lengths -> offsets ----
        int v = sum2;
        #pragma unroll
        for (int d = 1; d < 64; d <<= 1) { int u = __shfl_up(v, d, 64); if (lane >= d) v += u; }
        if (lane == 63) wsum[wave] = v;
        __syncthreads();
        if (wave == 0 && lane < 16) {
            int w = wsum[lane];
            #pragma unroll
            for (int d = 1; d < 16; d <<= 1) { int u = __shfl_up(w, d, 64); if (lane >= d) w += u; }
            wsum[lane] = w;
        }
        __syncthreads();
        const int clen = carry[0];
        const int cbase = (wave > 0) ? wsum[wave - 1] : 0;
        const int excl = clen + cbase + v - sum2;        // offset of i0
        const int off0 = excl, off1 = excl + a;
        if (i0 < n_seg) offsets[i0] = off0;
        if (i1 < n_seg) offsets[i1] = off1;
        const int chunk_len = wsum[15];
        __syncthreads();

        // ---- scan of fast-tile counts -> tprefix (+ optional flat map) ----
        const int f0 = (i0 < n_seg && (off0 & 15) == 0) ? (a >> 6) : 0;
        const int f1 = (i1 < n_seg && (off1 & 15) == 0) ? (b >> 6) : 0;
        int fv = f0 + f1;
        #pragma unroll
        for (int d = 1; d < 64; d <<= 1) { int u = __shfl_up(fv, d, 64); if (lane >= d) fv += u; }
        if (lane == 63) wsum[wave] = fv;
        __syncthreads();
        if (wave == 0 && lane < 16) {
            int w = wsum[lane];
            #pragma unroll
            for (int d = 1; d < 16; d <<= 1) { int u = __shfl_up(w, d, 64); if (lane >= d) w += u; }
            wsum[lane] = w;
        }
        __syncthreads();
        const int ctile = carry[1];
        const int fcbase = (wave > 0) ? wsum[wave - 1] : 0;
        const int fincl = ctile + fcbase + fv;           // inclusive through i1
        const int tb1 = fincl - f1;                      // first tile of i1
        const int tb0 = tb1 - f0;                        // first tile of i0
        if (i0 < n_seg) tprefix[i0] = tb1;               // inclusive through i0
        if (i1 < n_seg) tprefix[i1] = fincl;
        if (use_map) {
            for (int k = 0; k < f0; ++k) { seg_of[tb0 + k] = i0; loc_of[tb0 + k] = k; }
            for (int k = 0; k < f1; ++k) { seg_of[tb1 + k] = i1; loc_of[tb1 + k] = k; }
        }
        const int chunk_tile = wsum[15];
        __syncthreads();
        if (t == 0) { carry[0] = clen + chunk_len; carry[1] = ctile + chunk_tile; }
        __syncthreads();
    }
}

template <bool USE_MAP>
__global__ __launch_bounds__(256) void emb_tile_kernel(const float* __restrict__ x,
                                                       const int* __restrict__ lengths,
                                                       const int* __restrict__ offsets,
                                                       const int* __restrict__ tprefix,
                                                       const int* __restrict__ seg_of,
                                                       const int* __restrict__ loc_of,
                                                       int n_seg,
                                                       float* __restrict__ out) {
    __shared__ alignas(16) float lt[4 * 2064];   // 33 KB: 16-row buffer per wave
    const int n_tiles = tprefix[n_seg - 1];
    const int tau = blockIdx.x;
    const int tid = threadIdx.x;

    if (tau < n_tiles) {
        int s, tloc;
        if (USE_MAP) {
            s = seg_of[tau];
            tloc = loc_of[tau];
        } else {
            int lo = 0, hi = n_seg - 1;
            while (lo < hi) { int mid = (lo + hi) >> 1; if (tprefix[mid] > tau) hi = mid; else lo = mid + 1; }
            s = lo;
            tloc = tau - ((s == 0) ? 0 : tprefix[s - 1]);
        }
        const int off = offsets[s];
        const int L = lengths[s];
        const float invL = 1.0f / (float)L;
        const float* __restrict__ xs = x + (size_t)off * 128;
        float* __restrict__ os = out + (size_t)off * 129;

        const int wave = tid >> 6, lane = tid & 63;
        float* __restrict__ lb = lt + wave * 2064;
        const int r0 = 64 * tloc + 16 * wave;            // this wave's 16 rows

        const f4* __restrict__ src = (const f4*)(xs + (size_t)r0 * 128);
        f4 a[8];
        #pragma unroll
        for (int p = 0; p < 8; ++p) a[p] = src[lane + 64 * p];

        #pragma unroll
        for (int p = 0; p < 8; ++p) {
            const int q = lane + 64 * p;                 // f4 index in 16x128 tile
            float* d = &lb[(q >> 5) * 129 + 1 + ((q & 31) << 2)];
            d[0] = a[p].x; d[1] = a[p].y; d[2] = a[p].z; d[3] = a[p].w;
        }
        if (lane < 16) lb[lane * 129] = (float)(r0 + lane + 1) * invL;

        const f4* __restrict__ l4 = (const f4*)lb;
        f4* __restrict__ o4 = (f4*)(os + (size_t)r0 * 129);
        #pragma unroll
        for (int p = 0; p < 8; ++p) o4[lane + 64 * p] = l4[lane + 64 * p];
        if (lane < 4) o4[512 + lane] = l4[512 + lane];
    } else if (tau - n_tiles < n_seg) {
        // ragged tail / unaligned-segment fallback (no-op for uniform input)
        const int s = tau - n_tiles;
        const int off = offsets[s];
        const int L = lengths[s];
        if (L <= 0) return;
        const float invL = 1.0f / (float)L;
        const float* __restrict__ xs = x + (size_t)off * 128;
        float* __restrict__ os = out + (size_t)off * 129;
        const int f = ((off & 15) == 0) ? (L >> 6) : 0;
        const int e0 = f * 64 * 129;
        const int E = L * 129;
        for (int e = e0 + tid; e < E; e += 256) {
            const int row = e / 129;
            const int c = e - row * 129;
            os[e] = (c == 0) ? (float)(row + 1) * invL
                             : xs[(size_t)row * 128 + (c - 1)];
        }
    }
}

extern "C" void kernel_launch(void* const* d_in, const int* in_sizes, int n_in,
                              void* d_out, int out_size, void* d_ws, size_t ws_size,
                              hipStream_t stream) {
    const float* x = (const float*)d_in[0];
    const int* lengths = (const int*)d_in[1];
    const int n_seg = in_sizes[1];
    const int rows = in_sizes[0] / 128;
    const int maxt = rows / 64;

    int* offsets = (int*)d_ws;
    int* tprefix = offsets + n_seg;
    int* seg_of  = tprefix + n_seg;
    int* loc_of  = seg_of + maxt;
    const size_t need = (size_t)(2 * n_seg + 2 * maxt) * sizeof(int);
    const bool use_map = (ws_size >= need);

    scan_kernel<<<1, 1024, 0, stream>>>(lengths, offsets, tprefix,
                                        seg_of, loc_of, n_seg, use_map ? 1 : 0);

    const int grid = maxt + n_seg;       // fast tiles + tail blocks
    if (grid > 0) {
        if (use_map)
            emb_tile_kernel<true><<<grid, 256, 0, stream>>>(x, lengths, offsets, tprefix,
                                                            seg_of, loc_of, n_seg, (float*)d_out);
        else
            emb_tile_kernel<false><<<grid, 256, 0, stream>>>(x, lengths, offsets, tprefix,
                                                             seg_of, loc_of, n_seg, (float*)d_out);
    }
}

// Round 10
// 199.105 us; speedup vs baseline: 1.0910x; 1.0910x over previous
//
#include <hip/hip_runtime.h>

typedef float f4 __attribute__((ext_vector_type(4)));
typedef int i4 __attribute__((ext_vector_type(4)));

// ---------------------------------------------------------------------------
// R10: sequential-front tile kernel with FUSED per-block mapping scan.
// grid = maxt + n_seg. Block tau < maxt handles global 64-row output tile tau
// (consecutive blocks -> consecutive 33 KB output windows, copy/fill-like
// DRAM front). Each block locates its (segment s, local tile tloc, offset)
// via a block-wide double scan of lengths (L2-broadcast, concurrent across
// blocks -> hidden, unlike R9's serial scan kernel). x loads are issued
// SPECULATIVELY at block start with the uniform-mapping guess row=64*tau
// (always in-bounds; verified post-scan, reloaded iff ragged layout differs)
// so scan math overlaps HBM read latency. Blocks tau >= maxt handle ragged
// tails / unaligned segments (no-op for uniform lengths).
// ---------------------------------------------------------------------------
__global__ __launch_bounds__(256) void emb_kernel(const float* __restrict__ x,
                                                  const int* __restrict__ lengths,
                                                  float* __restrict__ out,
                                                  int n_seg, int maxt) {
    __shared__ alignas(16) float lt[4 * 2064];   // 33 KB: 16-row buffer per wave
    __shared__ int sw[4];                         // cross-wave scan partials
    __shared__ int sres[4];                       // off, L, tloc, found
    const int tid = threadIdx.x;
    const int lane = tid & 63, wave = tid >> 6;
    const int tau = blockIdx.x;

    if (tau < maxt) {
        if (tid == 0) sres[3] = 0;

        // ---- lengths loads FIRST (chunk 0), so scan waits only on these ----
        int l[8];
        const int i0 = tid * 8;
        if (i0 + 8 <= n_seg) {
            const i4* lp = (const i4*)(lengths + i0);
            const i4 u0 = lp[0], u1 = lp[1];
            l[0] = u0.x; l[1] = u0.y; l[2] = u0.z; l[3] = u0.w;
            l[4] = u1.x; l[5] = u1.y; l[6] = u1.z; l[7] = u1.w;
        } else {
            #pragma unroll
            for (int j = 0; j < 8; ++j) l[j] = (i0 + j < n_seg) ? lengths[i0 + j] : 0;
        }

        // ---- speculative x loads: uniform-mapping guess row = 64*tau ----
        // Always in-bounds: 64*tau + 63 < 64*maxt <= rows.
        f4 a[8];
        {
            const f4* gsrc = (const f4*)(x + (size_t)(64 * tau + 16 * wave) * 128);
            #pragma unroll
            for (int p = 0; p < 8; ++p) a[p] = gsrc[lane + 64 * p];
        }
        __syncthreads();                          // sres[3] init visible

        // ---- chunked block-wide double scan to locate tile tau ----
        int carry_rows = 0, carry_tiles = 0;
        for (int base = 0; base < n_seg; base += 2048) {
            if (base > 0) {                       // later chunks (n_seg > 2048)
                const int ii = base + tid * 8;
                #pragma unroll
                for (int j = 0; j < 8; ++j) l[j] = (ii + j < n_seg) ? lengths[ii + j] : 0;
            }
            const int th_rows = l[0]+l[1]+l[2]+l[3]+l[4]+l[5]+l[6]+l[7];
            int incl = th_rows;
            #pragma unroll
            for (int d = 1; d < 64; d <<= 1) { int u = __shfl_up(incl, d, 64); if (lane >= d) incl += u; }
            if (lane == 63) sw[wave] = incl;
            __syncthreads();
            const int w0 = sw[0], w1 = sw[1], w2 = sw[2], w3 = sw[3];
            __syncthreads();
            const int wbase = (wave > 0 ? w0 : 0) + (wave > 1 ? w1 : 0) + (wave > 2 ? w2 : 0);
            const int rows_total = w0 + w1 + w2 + w3;

            int run = carry_rows + wbase + incl - th_rows;
            int offj[8], f[8]; int th_tiles = 0;
            #pragma unroll
            for (int j = 0; j < 8; ++j) {
                offj[j] = run; run += l[j];
                f[j] = ((offj[j] & 15) == 0) ? (l[j] >> 6) : 0;
                th_tiles += f[j];
            }
            int tincl = th_tiles;
            #pragma unroll
            for (int d = 1; d < 64; d <<= 1) { int u = __shfl_up(tincl, d, 64); if (lane >= d) tincl += u; }
            if (lane == 63) sw[wave] = tincl;
            __syncthreads();
            const int t0 = sw[0], t1 = sw[1], t2 = sw[2], t3 = sw[3];
            __syncthreads();
            const int tbase = (wave > 0 ? t0 : 0) + (wave > 1 ? t1 : 0) + (wave > 2 ? t2 : 0);
            const int tiles_total = t0 + t1 + t2 + t3;

            const int rel = tau - carry_tiles - (tbase + tincl - th_tiles);
            if (rel >= 0 && rel < th_tiles) {
                int cum = 0;
                #pragma unroll
                for (int j = 0; j < 8; ++j) {
                    if (rel >= cum && rel < cum + f[j]) {
                        sres[0] = offj[j]; sres[1] = l[j]; sres[2] = rel - cum; sres[3] = 1;
                    }
                    cum += f[j];
                }
            }
            carry_rows += rows_total; carry_tiles += tiles_total;
            __syncthreads();
            if (sres[3]) break;                   // uniform read-after-sync
        }
        if (!sres[3]) return;                     // tau >= n_tiles: idle
        const int off = sres[0], L = sres[1], tloc = sres[2];

        // ---- verify speculation; reload iff ragged mapping differs ----
        const int gr = off + 64 * tloc;           // actual global start row
        if (gr != 64 * tau) {
            const f4* src2 = (const f4*)(x + (size_t)(gr + 16 * wave) * 128);
            #pragma unroll
            for (int p = 0; p < 8; ++p) a[p] = src2[lane + 64 * p];
        }

        // ---- proven full-line wave-private LDS-bounce body ----
        const float invL = 1.0f / (float)L;
        const int r0 = 64 * tloc + 16 * wave;     // segment-relative row
        float* __restrict__ lb = lt + wave * 2064;
        #pragma unroll
        for (int p = 0; p < 8; ++p) {
            const int q = lane + 64 * p;          // f4 index in 16x128 tile
            float* d = &lb[(q >> 5) * 129 + 1 + ((q & 31) << 2)];
            d[0] = a[p].x; d[1] = a[p].y; d[2] = a[p].z; d[3] = a[p].w;
        }
        if (lane < 16) lb[lane * 129] = (float)(r0 + lane + 1) * invL;

        const f4* __restrict__ l4 = (const f4*)lb;
        f4* __restrict__ o4 = (f4*)(out + ((size_t)off + r0) * 129);
        #pragma unroll
        for (int p = 0; p < 8; ++p) o4[lane + 64 * p] = l4[lane + 64 * p];
        if (lane < 4) o4[512 + lane] = l4[512 + lane];
    } else {
        // ---- ragged tail / unaligned-segment fallback (no-op when uniform) ----
        const int s = tau - maxt;
        if (s >= n_seg) return;
        int partial = 0;
        for (int i = tid; i < s; i += 256) partial += lengths[i];
        #pragma unroll
        for (int d = 32; d > 0; d >>= 1) partial += __shfl_xor(partial, d, 64);
        if (lane == 0) sw[wave] = partial;
        __syncthreads();
        const int off = sw[0] + sw[1] + sw[2] + sw[3];
        const int L = lengths[s];
        if (L <= 0) return;
        const float invL = 1.0f / (float)L;
        const float* __restrict__ xs = x + (size_t)off * 128;
        float* __restrict__ os = out + (size_t)off * 129;
        const int f = ((off & 15) == 0) ? (L >> 6) : 0;
        const int E = L * 129;
        for (int e = f * 64 * 129 + tid; e < E; e += 256) {
            const int row = e / 129;
            const int c = e - row * 129;
            os[e] = (c == 0) ? (float)(row + 1) * invL
                             : xs[(size_t)row * 128 + (c - 1)];
        }
    }
}

extern "C" void kernel_launch(void* const* d_in, const int* in_sizes, int n_in,
                              void* d_out, int out_size, void* d_ws, size_t ws_size,
                              hipStream_t stream) {
    const float* x = (const float*)d_in[0];
    const int* lengths = (const int*)d_in[1];
    const int n_seg = in_sizes[1];
    const int rows = in_sizes[0] / 128;
    const int maxt = rows / 64;

    emb_kernel<<<maxt + n_seg, 256, 0, stream>>>(x, lengths, (float*)d_out, n_seg, maxt);
}